// Round 6
// baseline (978.592 us; speedup 1.0000x reference)
//
#include <hip/hip_runtime.h>
#include <hip/hip_bf16.h>

#define BATCH 4
#define IMG 224
#define CDIM 256
#define WS 7
#define NWIN 4096
#define NTOK 49
#define TTOK 200704
#define HEADS 8
#define HD 32
#define SCALE 0.5f
#define LN_EPS 1e-5f

typedef __attribute__((ext_vector_type(8))) short short8v;
typedef __attribute__((ext_vector_type(4))) float f32x4;
typedef unsigned short u16;

__device__ __forceinline__ u16 f2bf(float f) {
  __hip_bfloat16 h = __float2bfloat16(f);
  return *reinterpret_cast<u16*>(&h);
}

__device__ __forceinline__ void gld_lds16(const void* g, void* l) {
  __builtin_amdgcn_global_load_lds(
      (const __attribute__((address_space(1))) unsigned int*)g,
      (__attribute__((address_space(3))) unsigned int*)l, 16, 0, 0);
}

// ---------------------------------------------------------------------------
// K0a: gather window-partitioned x and convert to bf16: xb[TTOK][256]
// ---------------------------------------------------------------------------
__global__ __launch_bounds__(256) void pack_x(const float* __restrict__ x,
                                              u16* __restrict__ xb) {
  const int NCH = TTOK * 32;  // 8-elem chunks
  for (int id = blockIdx.x * 256 + threadIdx.x; id < NCH; id += 2048 * 256) {
    int t = id >> 5;
    int cc = (id & 31) << 3;
    int wq = t / 49, n = t - wq * 49;
    int b = wq >> 10, rem = wq & 1023;
    int gh = (rem >> 5) * 7 + n / 7;
    int gw = (rem & 31) * 7 + n % 7;
    const float* src = x + (((size_t)b * IMG + gh) * IMG + gw) * CDIM + cc;
    float4 f0 = *(const float4*)src;
    float4 f1 = *(const float4*)(src + 4);
    union { u16 us[8]; uint4 v; } pk;
    pk.us[0] = f2bf(f0.x); pk.us[1] = f2bf(f0.y);
    pk.us[2] = f2bf(f0.z); pk.us[3] = f2bf(f0.w);
    pk.us[4] = f2bf(f1.x); pk.us[5] = f2bf(f1.y);
    pk.us[6] = f2bf(f1.z); pk.us[7] = f2bf(f1.w);
    *(uint4*)(xb + (size_t)id * 8) = pk.v;
  }
}

// ---------------------------------------------------------------------------
// K0b: transpose+convert weights to N-major bf16: wqkvT[n][k], woutT[n][k]
// ---------------------------------------------------------------------------
__global__ __launch_bounds__(256) void pack_w(const float* __restrict__ wqkv,
                                              const float* __restrict__ wout,
                                              u16* __restrict__ wqkvT,
                                              u16* __restrict__ woutT) {
  int id = blockIdx.x * 256 + threadIdx.x;  // 262144
  if (id < 196608) {
    int nn = id >> 8, k = id & 255;
    wqkvT[id] = f2bf(wqkv[(size_t)k * 768 + nn]);
  } else {
    int id2 = id - 196608;
    int nn = id2 >> 8, k = id2 & 255;
    woutT[id2] = f2bf(wout[(size_t)k * 256 + nn]);
  }
}

// ---------------------------------------------------------------------------
// K1: QKV GEMM, bf16 MFMA, 128(t) x 128(n) tile, FULL K=256 staged once
// (64KB A + 64KB B LDS, 1 block/CU), ONE barrier, then 8 barrier-free
// MFMA steps. Operands swapped (A-op = weights, B-op = tokens) so the
// C-quad runs along n -> 8B vectorized stores to natural [t][768] layout.
// ---------------------------------------------------------------------------
__global__ __launch_bounds__(256) void qkv_gemm(const u16* __restrict__ xb,
                                                const u16* __restrict__ wqkvT,
                                                const float* __restrict__ bqkv,
                                                u16* __restrict__ qkvb) {
  __shared__ __align__(16) short As[32768];  // weights: [8 ks][8 sub][64 lane][8]
  __shared__ __align__(16) short Bs[32768];  // tokens : same layout

  int tid = threadIdx.x;
  int lane = tid & 63, wid = tid >> 6;
  int wn = wid >> 1, wt = wid & 1;  // wave: n-half, t-half
  // grid = 9408 = 8 * 1176; bijective XCD swizzle (nwg % 8 == 0)
  int hb = blockIdx.x;
  int bid = (hb & 7) * 1176 + (hb >> 3);
  int mt = bid / 6, nt = bid % 6;
  int m0 = mt * 128, n0 = nt * 128;

  // stage everything: per ks (8): 512 16B-chunks per matrix, 2 per thread
#pragma unroll
  for (int ks = 0; ks < 8; ++ks) {
#pragma unroll
    for (int i = 0; i < 2; ++i) {
      int c = i * 256 + tid;
      int l6 = c & 63;
      int rr = ((c >> 6) << 4) + (l6 & 15);
      int kk = ks * 32 + ((l6 >> 4) << 3);
      gld_lds16(wqkvT + (size_t)(n0 + rr) * 256 + kk, &As[ks * 4096 + c * 8]);
      gld_lds16(xb + (size_t)(m0 + rr) * 256 + kk, &Bs[ks * 4096 + c * 8]);
    }
  }

  f32x4 zero = {0.f, 0.f, 0.f, 0.f};
  f32x4 acc[4][4];  // [nsub][tsub]
#pragma unroll
  for (int n = 0; n < 4; ++n)
#pragma unroll
    for (int t = 0; t < 4; ++t) acc[n][t] = zero;

  __syncthreads();  // single drain

#pragma unroll
  for (int ks = 0; ks < 8; ++ks) {
    short8v af[4], bfv[4];
#pragma unroll
    for (int n = 0; n < 4; ++n)
      af[n] = *(const short8v*)&As[ks * 4096 + ((wn * 4 + n) * 64 + lane) * 8];
#pragma unroll
    for (int t = 0; t < 4; ++t)
      bfv[t] = *(const short8v*)&Bs[ks * 4096 + ((wt * 4 + t) * 64 + lane) * 8];
#pragma unroll
    for (int n = 0; n < 4; ++n)
#pragma unroll
      for (int t = 0; t < 4; ++t)
        acc[n][t] = __builtin_amdgcn_mfma_f32_16x16x32_bf16(af[n], bfv[t],
                                                            acc[n][t], 0, 0, 0);
  }

  // epilogue: C row = n (quad over j), col = t. 8B stores to [t][768].
  int cl = lane & 15, fq = lane >> 4;
#pragma unroll
  for (int n = 0; n < 4; ++n) {
    int nb = n0 + wn * 64 + n * 16 + fq * 4;  // 4 consecutive n
    float4 bq = *(const float4*)(bqkv + nb);
#pragma unroll
    for (int t = 0; t < 4; ++t) {
      int tr = m0 + wt * 64 + t * 16 + cl;
      union { u16 us[4]; uint2 v; } pk;
      pk.us[0] = f2bf(acc[n][t][0] + bq.x);
      pk.us[1] = f2bf(acc[n][t][1] + bq.y);
      pk.us[2] = f2bf(acc[n][t][2] + bq.z);
      pk.us[3] = f2bf(acc[n][t][3] + bq.w);
      *(uint2*)(qkvb + (size_t)tr * 768 + nb) = pk.v;
    }
  }
}

// ---------------------------------------------------------------------------
// K2: MFMA attention. One wave per (window, head); 4 waves/block.
// Q/K frags direct from global [t][768]; V transposed into LDS; P via LDS.
// Cols >= 49 masked to -1e30. Writes attnb bf16 [t][256].
// ---------------------------------------------------------------------------
__global__ __launch_bounds__(256) void attn_kernel(
    const u16* __restrict__ qkvb, const float* __restrict__ bias_table,
    u16* __restrict__ attnb) {
  __shared__ u16 Pl[4][4096];       // 64x64 bf16, XOR-swizzled
  __shared__ u16 Vl[4][32 * 72];    // V^T: [d][k], stride 72
  __shared__ float bsh[4][169];

  int bid = blockIdx.x;  // NWIN*2
  int w = bid >> 1;
  int wid = threadIdx.x >> 6, lane = threadIdx.x & 63;
  int h = ((bid & 1) << 2) | wid;
  int cl = lane & 15, cg = lane >> 4;

  for (int i = lane; i < 169; i += 64)
    bsh[wid][i] = bias_table[i * HEADS + h];

  const u16* rowb = qkvb + (size_t)w * 49 * 768;
  const u16* qp = rowb + h * 32;          // q cols [0,256)
  const u16* kp = rowb + 256 + h * 32;    // k cols
  const u16* vp = rowb + 512 + h * 32;    // v cols

  // Q/K fragments (A-frag layout: row = lane&15, k = (lane>>4)*8 + j)
  short8v qf[4], kf[4];
#pragma unroll
  for (int mt = 0; mt < 4; ++mt) {
    int off = (mt * 16 + cl) * 768 + cg * 8;
    qf[mt] = *(const short8v*)(qp + off);
    kf[mt] = *(const short8v*)(kp + off);
  }

  // stage V transposed into LDS: Vl[d][k], zero-fill k >= 49
  short8v vz = {0, 0, 0, 0, 0, 0, 0, 0};
#pragma unroll
  for (int pass = 0; pass < 4; ++pass) {
    int cidx = pass * 64 + lane;
    int t = cidx >> 2, dc = (cidx & 3) * 8;
    short8v vv = (t < 49) ? *(const short8v*)(vp + (size_t)t * 768 + dc) : vz;
#pragma unroll
    for (int j = 0; j < 8; ++j) Vl[wid][(dc + j) * 72 + t] = vv[j];
  }

  // S = Q K^T  (16 MFMAs, K=32 = full head dim)
  f32x4 zero4 = {0.f, 0.f, 0.f, 0.f};
  f32x4 s[4][4];
#pragma unroll
  for (int mt = 0; mt < 4; ++mt)
#pragma unroll
    for (int nt = 0; nt < 4; ++nt)
      s[mt][nt] = __builtin_amdgcn_mfma_f32_16x16x32_bf16(qf[mt], kf[nt],
                                                          zero4, 0, 0, 0);

  // key-side bias decomposition (col = nt*16 + cl)
  int kr7[4], kc7[4];
#pragma unroll
  for (int nt = 0; nt < 4; ++nt) {
    int col = nt * 16 + cl;
    kr7[nt] = (col * 9363) >> 16;
    kc7[nt] = col - kr7[nt] * 7;
  }

  // bias + scale + mask, then softmax per row (C-layout: row=cg*4+r)
  f32x4 rinv[4];
#pragma unroll
  for (int mt = 0; mt < 4; ++mt) {
#pragma unroll
    for (int r = 0; r < 4; ++r) {
      int row = mt * 16 + cg * 4 + r;
      int qr = (row * 9363) >> 16;
      int qc = row - qr * 7;
      float sv[4];
#pragma unroll
      for (int nt = 0; nt < 4; ++nt) {
        int col = nt * 16 + cl;
        if (col < 49) {
          int idx = (qr - kr7[nt] + 6) * 13 + (qc - kc7[nt] + 6);
          sv[nt] = s[mt][nt][r] * SCALE + bsh[wid][idx];
        } else {
          sv[nt] = -1e30f;
        }
      }
      float m = fmaxf(fmaxf(sv[0], sv[1]), fmaxf(sv[2], sv[3]));
#pragma unroll
      for (int msk = 1; msk < 16; msk <<= 1) m = fmaxf(m, __shfl_xor(m, msk));
      float sum = 0.f;
#pragma unroll
      for (int nt = 0; nt < 4; ++nt) {
        float p = __expf(sv[nt] - m);
        s[mt][nt][r] = p;
        sum += p;
      }
#pragma unroll
      for (int msk = 1; msk < 16; msk <<= 1) sum += __shfl_xor(sum, msk);
      rinv[mt][r] = 1.0f / sum;
    }
  }

  // write P (bf16) to LDS, XOR-swizzled on element index
#pragma unroll
  for (int mt = 0; mt < 4; ++mt)
#pragma unroll
    for (int r = 0; r < 4; ++r) {
      int row = mt * 16 + cg * 4 + r;
      int swz = (row & 7) << 3;
#pragma unroll
      for (int nt = 0; nt < 4; ++nt) {
        int col = nt * 16 + cl;
        Pl[wid][(row * 64 + col) ^ swz] = f2bf(s[mt][nt][r]);
      }
    }

  // O = P V   (A = P from LDS, B = V^T rows from LDS)
  f32x4 o[4][2];
#pragma unroll
  for (int mt = 0; mt < 4; ++mt)
#pragma unroll
    for (int nt2 = 0; nt2 < 2; ++nt2) o[mt][nt2] = zero4;

#pragma unroll
  for (int kt = 0; kt < 2; ++kt) {
    short8v vfr[2];
#pragma unroll
    for (int nt2 = 0; nt2 < 2; ++nt2)
      vfr[nt2] = *(const short8v*)&Vl[wid][(nt2 * 16 + cl) * 72 + kt * 32 + cg * 8];
#pragma unroll
    for (int mt = 0; mt < 4; ++mt) {
      int row = mt * 16 + cl;
      short8v pa = *(const short8v*)
          &Pl[wid][(row * 64 + kt * 32 + cg * 8) ^ ((row & 7) << 3)];
#pragma unroll
      for (int nt2 = 0; nt2 < 2; ++nt2)
        o[mt][nt2] = __builtin_amdgcn_mfma_f32_16x16x32_bf16(pa, vfr[nt2],
                                                             o[mt][nt2], 0, 0, 0);
    }
  }

  // store rows < 49, scaled by 1/rowsum
#pragma unroll
  for (int mt = 0; mt < 4; ++mt)
#pragma unroll
    for (int r = 0; r < 4; ++r) {
      int row = mt * 16 + cg * 4 + r;
      if (row < 49) {
        float ri = rinv[mt][r];
        size_t dst = (size_t)(w * 49 + row) * 256 + h * 32;
#pragma unroll
        for (int nt2 = 0; nt2 < 2; ++nt2)
          attnb[dst + nt2 * 16 + cl] = f2bf(o[mt][nt2][r] * ri);
      }
    }
}

// ---------------------------------------------------------------------------
// K3: out-proj MFMA + bias + residual + LayerNorm. BM=128, BK=32, 8 waves.
// ---------------------------------------------------------------------------
__global__ __launch_bounds__(512) void out_ln_kernel(
    const u16* __restrict__ attnb, const u16* __restrict__ woutT,
    const float* __restrict__ bout, const float* __restrict__ x,
    const float* __restrict__ gamma, const float* __restrict__ beta,
    float* __restrict__ out) {
  __shared__ __align__(16) short As[2][4096];
  __shared__ __align__(16) short Bs[2][8192];
  __shared__ float ls1[128], ls2[128];
  __shared__ int rowoff_s[128];

  int tid = threadIdx.x;
  int lane = tid & 63, wid = tid >> 6;
  int wm = wid >> 2, wn = wid & 3;
  int m0 = blockIdx.x * 128;

  if (tid < 128) {
    ls1[tid] = 0.f;
    ls2[tid] = 0.f;
    int t = m0 + tid;
    int wq = t / 49, n = t - wq * 49;
    int b = wq >> 10, rem = wq & 1023;
    int gh = (rem >> 5) * 7 + n / 7;
    int gw = (rem & 31) * 7 + n % 7;
    rowoff_s[tid] = ((b * IMG + gh) * IMG + gw) * CDIM;
  }

  f32x4 zero = {0.f, 0.f, 0.f, 0.f};
  f32x4 acc[4][4];
#pragma unroll
  for (int m = 0; m < 4; ++m)
#pragma unroll
    for (int n = 0; n < 4; ++n) acc[m][n] = zero;

#define STAGE_K3(buf, k0)                                                 \
  {                                                                       \
    {                                                                     \
      int c = tid;                                                        \
      int l6 = c & 63;                                                    \
      int rr = ((c >> 6) << 4) + (l6 & 15);                               \
      int kk = (k0) + ((l6 >> 4) << 3);                                   \
      gld_lds16(attnb + (size_t)(m0 + rr) * 256 + kk, &As[buf][c * 8]);   \
    }                                                                     \
    _Pragma("unroll") for (int i = 0; i < 2; ++i) {                       \
      int c = i * 512 + tid;                                              \
      int l6 = c & 63;                                                    \
      int cc = ((c >> 6) << 4) + (l6 & 15);                               \
      int kk = (k0) + ((l6 >> 4) << 3);                                   \
      gld_lds16(woutT + (size_t)cc * 256 + kk, &Bs[buf][c * 8]);          \
    }                                                                     \
  }

  STAGE_K3(0, 0);
  __syncthreads();

  int buf = 0;
  for (int ks = 0; ks < 8; ++ks) {
    if (ks < 7) STAGE_K3(buf ^ 1, (ks + 1) * 32);
    short8v af[4], bfv[4];
#pragma unroll
    for (int m = 0; m < 4; ++m)
      af[m] = *(const short8v*)&As[buf][((wm * 4 + m) * 64 + lane) * 8];
#pragma unroll
    for (int n = 0; n < 4; ++n)
      bfv[n] = *(const short8v*)&Bs[buf][((wn * 4 + n) * 64 + lane) * 8];
#pragma unroll
    for (int m = 0; m < 4; ++m)
#pragma unroll
      for (int n = 0; n < 4; ++n)
        acc[m][n] = __builtin_amdgcn_mfma_f32_16x16x32_bf16(af[m], bfv[n],
                                                            acc[m][n], 0, 0, 0);
    __syncthreads();
    buf ^= 1;
  }

  int fr = lane & 15, fq = lane >> 4;
#pragma unroll
  for (int m = 0; m < 4; ++m) {
#pragma unroll
    for (int r = 0; r < 4; ++r) {
      int lrow = wm * 64 + m * 16 + fq * 4 + r;
      const float* xr = x + rowoff_s[lrow];
      float s1 = 0.f, s2 = 0.f;
#pragma unroll
      for (int n = 0; n < 4; ++n) {
        int c = wn * 64 + n * 16 + fr;
        float v = acc[m][n][r] + bout[c] + xr[c];
        acc[m][n][r] = v;
        s1 += v;
        s2 += v * v;
      }
#pragma unroll
      for (int off = 1; off < 16; off <<= 1) {
        s1 += __shfl_xor(s1, off);
        s2 += __shfl_xor(s2, off);
      }
      if (fr == 0) {
        atomicAdd(&ls1[lrow], s1);
        atomicAdd(&ls2[lrow], s2);
      }
    }
  }
  __syncthreads();

#pragma unroll
  for (int m = 0; m < 4; ++m) {
#pragma unroll
    for (int r = 0; r < 4; ++r) {
      int lrow = wm * 64 + m * 16 + fq * 4 + r;
      float mean = ls1[lrow] * (1.0f / 256.0f);
      float var = ls2[lrow] * (1.0f / 256.0f) - mean * mean;
      float rstd = rsqrtf(var + LN_EPS);
      size_t orow = (size_t)(m0 + lrow) * 256;
#pragma unroll
      for (int n = 0; n < 4; ++n) {
        int c = wn * 64 + n * 16 + fr;
        out[orow + c] = (acc[m][n][r] - mean) * rstd * gamma[c] + beta[c];
      }
    }
  }
}

extern "C" void kernel_launch(void* const* d_in, const int* in_sizes, int n_in,
                              void* d_out, int out_size, void* d_ws, size_t ws_size,
                              hipStream_t stream) {
  const float* x     = (const float*)d_in[0];
  const float* wqkv  = (const float*)d_in[1];
  const float* bqkv  = (const float*)d_in[2];
  const float* btab  = (const float*)d_in[3];
  const float* wout  = (const float*)d_in[4];
  const float* bout  = (const float*)d_in[5];
  const float* gamma = (const float*)d_in[6];
  const float* beta  = (const float*)d_in[7];
  float* out = (float*)d_out;

  u16* qkvb  = (u16*)d_ws;                        // [TTOK][768] bf16 = 308 MB
  u16* xb    = qkvb + (size_t)TTOK * 768;         // [TTOK][256] bf16 = 103 MB
  u16* attnb = xb;                                // reused after qkv_gemm
  u16* wqkvT = xb + (size_t)TTOK * 256;
  u16* woutT = wqkvT + 196608;

  pack_x<<<2048, 256, 0, stream>>>(x, xb);
  pack_w<<<1024, 256, 0, stream>>>(wqkv, wout, wqkvT, woutT);
  qkv_gemm<<<(TTOK / 128) * 6, 256, 0, stream>>>(xb, wqkvT, bqkv, qkvb);
  attn_kernel<<<NWIN * 2, 256, 0, stream>>>(qkvb, btab, attnb);
  out_ln_kernel<<<TTOK / 128, 512, 0, stream>>>(attnb, woutT, bout, x, gamma,
                                                beta, out);
}